// Round 1
// baseline (137.021 us; speedup 1.0000x reference)
//
#include <hip/hip_runtime.h>
#include <stdint.h>

#define NBINS 4096
#define CAP   65536

// Distance key: f32 bit pattern of sqrt((dx*dx + dy*dy) + dz*dz), computed with
// explicit round-to-nearest intrinsics so hipcc cannot FMA-contract and diverge
// from the numpy reference. Non-negative floats are order-isomorphic to their
// uint32 bit patterns.
__device__ __forceinline__ uint32_t dist_key(float x, float y, float z,
                                             float px, float py, float pz) {
    float dx = __fsub_rn(x, px);
    float dy = __fsub_rn(y, py);
    float dz = __fsub_rn(z, pz);
    float s = __fadd_rn(__fadd_rn(__fmul_rn(dx, dx), __fmul_rn(dy, dy)),
                        __fmul_rn(dz, dz));
    float d = __fsqrt_rn(s);
    return __float_as_uint(d);
}

__global__ void __launch_bounds__(256) zero_kernel(uint32_t* p, int n) {
    int i = blockIdx.x * 256 + threadIdx.x;
    if (i < n) p[i] = 0;
}

__global__ void __launch_bounds__(256) hist_kernel(const float* __restrict__ pts,
                                                   const float* __restrict__ P1,
                                                   uint32_t* __restrict__ ghist,
                                                   int nquads, int N) {
    __shared__ uint32_t lh[NBINS];
    for (int i = threadIdx.x; i < NBINS; i += 256) lh[i] = 0;
    __syncthreads();
    float px = P1[0], py = P1[1], pz = P1[2];
    int gid = blockIdx.x * 256 + threadIdx.x;
    int stride = gridDim.x * 256;
    const float4* p4 = (const float4*)pts;
    for (int q = gid; q < nquads; q += stride) {
        float4 a = p4[q * 3 + 0];
        float4 b = p4[q * 3 + 1];
        float4 c = p4[q * 3 + 2];
        uint32_t k0 = dist_key(a.x, a.y, a.z, px, py, pz);
        uint32_t k1 = dist_key(a.w, b.x, b.y, px, py, pz);
        uint32_t k2 = dist_key(b.z, b.w, c.x, px, py, pz);
        uint32_t k3 = dist_key(c.y, c.z, c.w, px, py, pz);
        atomicAdd(&lh[k0 >> 20], 1u);
        atomicAdd(&lh[k1 >> 20], 1u);
        atomicAdd(&lh[k2 >> 20], 1u);
        atomicAdd(&lh[k3 >> 20], 1u);
    }
    // tail (N not divisible by 4): handled by global thread 0
    if (gid == 0) {
        for (int i = nquads * 4; i < N; ++i) {
            uint32_t k = dist_key(pts[3 * i], pts[3 * i + 1], pts[3 * i + 2], px, py, pz);
            atomicAdd(&lh[k >> 20], 1u);
        }
    }
    __syncthreads();
    for (int i = threadIdx.x; i < NBINS; i += 256) {
        uint32_t v = lh[i];
        if (v) atomicAdd(&ghist[i], v);
    }
}

__global__ void __launch_bounds__(256) scan_kernel(const uint32_t* __restrict__ ghist,
                                                   uint32_t* __restrict__ cut, int K) {
    __shared__ uint32_t s[256];
    int t = threadIdx.x;
    uint32_t mine[16];
    uint32_t local = 0;
    for (int j = 0; j < 16; ++j) {
        mine[j] = ghist[t * 16 + j];
        local += mine[j];
    }
    s[t] = local;
    __syncthreads();
    // Hillis-Steele inclusive scan over 256 chunk sums
    for (int off = 1; off < 256; off <<= 1) {
        uint32_t v = (t >= off) ? s[t - off] : 0;
        __syncthreads();
        s[t] += v;
        __syncthreads();
    }
    uint32_t incl = s[t];
    uint32_t excl = incl - local;
    if (excl < (uint32_t)K && incl >= (uint32_t)K) {
        uint32_t run = excl;
        for (int j = 0; j < 16; ++j) {
            run += mine[j];
            if (run >= (uint32_t)K) {
                *cut = (uint32_t)(t * 16 + j);
                break;
            }
        }
    }
}

__global__ void __launch_bounds__(256) filter_kernel(const float* __restrict__ pts,
                                                     const float* __restrict__ P1,
                                                     const uint32_t* __restrict__ cut,
                                                     uint32_t* __restrict__ cnt,
                                                     uint32_t* __restrict__ ckeys,
                                                     uint32_t* __restrict__ cidx,
                                                     int nquads, int N) {
    float px = P1[0], py = P1[1], pz = P1[2];
    uint32_t cb = *cut;
    int gid = blockIdx.x * 256 + threadIdx.x;
    int stride = gridDim.x * 256;
    const float4* p4 = (const float4*)pts;
    for (int q = gid; q < nquads; q += stride) {
        float4 a = p4[q * 3 + 0];
        float4 b = p4[q * 3 + 1];
        float4 c = p4[q * 3 + 2];
        uint32_t k[4];
        k[0] = dist_key(a.x, a.y, a.z, px, py, pz);
        k[1] = dist_key(a.w, b.x, b.y, px, py, pz);
        k[2] = dist_key(b.z, b.w, c.x, px, py, pz);
        k[3] = dist_key(c.y, c.z, c.w, px, py, pz);
        #pragma unroll
        for (int j = 0; j < 4; ++j) {
            if ((k[j] >> 20) <= cb) {
                uint32_t pos = atomicAdd(cnt, 1u);
                if (pos < CAP) {
                    ckeys[pos] = k[j];
                    cidx[pos] = (uint32_t)(q * 4 + j);
                }
            }
        }
    }
    if (gid == 0) {
        for (int i = nquads * 4; i < N; ++i) {
            uint32_t kk = dist_key(pts[3 * i], pts[3 * i + 1], pts[3 * i + 2], px, py, pz);
            if ((kk >> 20) <= cb) {
                uint32_t pos = atomicAdd(cnt, 1u);
                if (pos < CAP) {
                    ckeys[pos] = kk;
                    cidx[pos] = (uint32_t)i;
                }
            }
        }
    }
}

__global__ void __launch_bounds__(256) select_kernel(const uint32_t* __restrict__ cnt,
                                                     const uint32_t* __restrict__ ckeys,
                                                     const uint32_t* __restrict__ cidx,
                                                     const float* __restrict__ pts,
                                                     float* __restrict__ out, int K) {
    __shared__ uint64_t red[256];
    __shared__ uint64_t sel[128];
    __shared__ uint64_t thresh_s;
    int t = threadIdx.x;
    uint32_t M = *cnt;
    if (M > CAP) M = CAP;
    if (K > 128) K = 128;
    if (t == 0) thresh_s = 0;
    __syncthreads();
    for (int k = 0; k < K; ++k) {
        uint64_t th = thresh_s;
        uint64_t local = ~0ULL;
        for (uint32_t j = t; j < M; j += 256) {
            uint64_t c = ((uint64_t)ckeys[j] << 32) | (uint64_t)cidx[j];
            if (c >= th && c < local) local = c;
        }
        red[t] = local;
        __syncthreads();
        for (int off = 128; off > 0; off >>= 1) {
            if (t < off) {
                uint64_t o = red[t + off];
                if (o < red[t]) red[t] = o;
            }
            __syncthreads();
        }
        if (t == 0) {
            sel[k] = red[0];
            thresh_s = red[0] + 1;
        }
        __syncthreads();
    }
    if (t < K) {
        uint64_t c = sel[t];
        uint32_t idx = (uint32_t)(c & 0xFFFFFFFFu);
        out[3 * t + 0] = pts[3 * idx + 0];
        out[3 * t + 1] = pts[3 * idx + 1];
        out[3 * t + 2] = pts[3 * idx + 2];
        out[3 * K + t] = (float)idx;  // indices exactly representable (< 2^23)
    }
}

extern "C" void kernel_launch(void* const* d_in, const int* in_sizes, int n_in,
                              void* d_out, int out_size, void* d_ws, size_t ws_size,
                              hipStream_t stream) {
    const float* pts = (const float*)d_in[0];
    const float* P1  = (const float*)d_in[1];
    float* out = (float*)d_out;

    int N = in_sizes[0] / 3;
    int nquads = N / 4;
    int K = out_size / 4;  // out = K*3 coords + K indices

    uint32_t* w    = (uint32_t*)d_ws;
    uint32_t* cnt  = w + 0;
    uint32_t* cut  = w + 1;
    uint32_t* hist = w + 2;            // NBINS
    uint32_t* ckeys = w + 2 + NBINS;   // CAP
    uint32_t* cidx  = ckeys + CAP;     // CAP

    int zn = 2 + NBINS;
    zero_kernel<<<(zn + 255) / 256, 256, 0, stream>>>(w, zn);
    hist_kernel<<<2048, 256, 0, stream>>>(pts, P1, hist, nquads, N);
    scan_kernel<<<1, 256, 0, stream>>>(hist, cut, K);
    filter_kernel<<<2048, 256, 0, stream>>>(pts, P1, cut, cnt, ckeys, cidx, nquads, N);
    select_kernel<<<1, 256, 0, stream>>>(cnt, ckeys, cidx, pts, out, K);
}